// Round 11
// baseline (579.097 us; speedup 1.0000x reference)
//
#include <hip/hip_runtime.h>
#include <cmath>

#define NN 100000
#define EE 1600000
#define DD 128
#define HH 128
#define SS 64
#define GG 512

#define NBE 782    // edge blocks of 2048
#define EBK 196    // dst buckets of 512 nodes
#define EHS 800    // ehist row stride

typedef float f32x4 __attribute__((ext_vector_type(4)));
typedef short s16x8 __attribute__((ext_vector_type(8)));

constexpr size_t alignup(size_t x){ return (x + 255) & ~(size_t)255; }
constexpr size_t SZ_P16   = (size_t)NN*64*sizeof(unsigned);       // 25.6MB packed bf16x2
constexpr size_t OFF_HW   = 0;                                     // BUF0
constexpr size_t OFF_H    = alignup(OFF_HW + SZ_P16);              // BUF1
constexpr size_t OFF_X16  = alignup(OFF_H + SZ_P16);              // bf16-packed x
constexpr size_t OFF_CSRS = alignup(OFF_X16 + SZ_P16);
constexpr size_t OFF_ROW  = alignup(OFF_CSRS + (size_t)EE*4);
constexpr size_t OFF_DINV = alignup(OFF_ROW + (size_t)(NN+1)*4);
constexpr size_t OFF_SATT = alignup(OFF_DINV + (size_t)NN*4);
constexpr size_t OFF_GST  = alignup(OFF_SATT + 64*4);             // start[513]
// sid-bucket machinery
constexpr size_t OFF_BH   = alignup(OFF_GST + 513*4);             // bhist [64][400]
constexpr size_t OFF_BO   = alignup(OFF_BH + (size_t)64*400*4);   // boff2 [64][400]
constexpr size_t OFF_TOT  = alignup(OFF_BO + (size_t)64*400*4);   // tots[64]
constexpr size_t OFF_ROW2 = alignup(OFF_TOT + 64*4);              // row2[65]
constexpr size_t OFF_LIST = alignup(OFF_ROW2 + 65*4);             // list[N]
constexpr size_t OFF_W16  = alignup(OFF_LIST + (size_t)NN*4);     // 4 x 8192
// edge-bucket machinery
constexpr size_t OFF_EH   = alignup(OFF_W16 + (size_t)4*8192*4);  // ehist [196][800]
constexpr size_t OFF_EB   = alignup(OFF_EH + (size_t)EBK*EHS*4);  // eboff [196][800]
constexpr size_t OFF_ET   = alignup(OFF_EB + (size_t)EBK*EHS*4);  // etots[196]
constexpr size_t OFF_EBASE= alignup(OFF_ET + EBK*4);              // ebase[197]
constexpr size_t OFF_EPK  = alignup(OFF_EBASE + 200*4);           // packed (dlocal<<17|src) [E]
// ---- zeroed region ----
constexpr size_t OFF_POOL = alignup(OFF_EPK + (size_t)EE*4);
constexpr size_t OFF_GSUM = alignup(OFF_POOL + (size_t)GG*HH*4);  // [8192]
constexpr size_t OFF_END  = alignup(OFF_GSUM + (size_t)SS*DD*4);
constexpr size_t ZERO_BEG   = OFF_POOL;
constexpr size_t ZERO_BYTES = OFF_END - OFF_POOL;

__device__ __forceinline__ unsigned pack2bf(float a, float b){
  unsigned ua = __float_as_uint(a); ua += 0x7fffu + ((ua >> 16) & 1u);
  unsigned ub = __float_as_uint(b); ub += 0x7fffu + ((ub >> 16) & 1u);
  return (ua >> 16) | (ub & 0xffff0000u);
}
__device__ __forceinline__ float bf_lo(unsigned u){ return __uint_as_float(u << 16); }
__device__ __forceinline__ float bf_hi(unsigned u){ return __uint_as_float(u & 0xffff0000u); }
__device__ __forceinline__ s16x8 as_s16x8(uint4 v){ union { uint4 u; s16x8 s; } x; x.u = v; return x.s; }

// ================= sid bucketing (for subst mean) =================
__global__ __launch_bounds__(256) void hist_kernel(const int* __restrict__ sid, int* __restrict__ bhist)
{
  __shared__ int h[64];
  int t = threadIdx.x, b = blockIdx.x;
  if (t < 64) h[t] = 0;
  __syncthreads();
  int n = b*256 + t;
  if (n < NN) atomicAdd(&h[sid[n]], 1);
  __syncthreads();
  if (t < 64) bhist[t*400 + b] = h[t];
}

__global__ __launch_bounds__(512) void offs_kernel(const int* __restrict__ bhist, int* __restrict__ boff2, int* __restrict__ tots)
{
  __shared__ int sh[512];
  int s = blockIdx.x, t = threadIdx.x;
  int v = (t < 391) ? bhist[s*400 + t] : 0;
  sh[t] = v;
  __syncthreads();
  for (int off = 1; off < 512; off <<= 1) {
    int u = (t >= off) ? sh[t - off] : 0;
    __syncthreads();
    sh[t] += u;
    __syncthreads();
  }
  if (t < 391) boff2[s*400 + t] = sh[t] - v;
  if (t == 511) tots[s] = sh[511];
}

__global__ __launch_bounds__(64) void base_kernel(const int* __restrict__ tots, int* __restrict__ row2)
{
  int l = threadIdx.x;
  int v = tots[l];
  int xv = v;
  #pragma unroll
  for (int off = 1; off < 64; off <<= 1) {
    int u = __shfl_up(xv, off, 64);
    if (l >= off) xv += u;
  }
  row2[l] = xv - v;
  if (l == 63) row2[64] = xv;
}

__global__ __launch_bounds__(256) void fill2_kernel(
    const int* __restrict__ sid, const int* __restrict__ row2,
    const int* __restrict__ boff2, unsigned* __restrict__ list)
{
  __shared__ int h[64];
  int t = threadIdx.x, b = blockIdx.x;
  if (t < 64) h[t] = 0;
  __syncthreads();
  int n = b*256 + t;
  if (n < NN) {
    int s = sid[n];
    int lr = atomicAdd(&h[s], 1);
    int pos = row2[s] + boff2[s*400 + b] + lr;
    list[pos] = ((unsigned)s << 24) | (unsigned)n;
  }
}

__global__ __launch_bounds__(256) void subst_sum(
    const unsigned* __restrict__ list, const float* __restrict__ x,
    float* __restrict__ gsum)
{
  int b = blockIdx.x, t = threadIdx.x;
  int lane = t & 63, w = t >> 6;
  const int per = (NN + 1023)/1024;   // 98
  const int q   = (per + 3)/4;        // 25
  int bend = min(b*per + per, NN);
  int beg = b*per + w*q;
  int end = min(bend, beg + q);
  if (beg >= end) return;
  int d0 = lane * 2;
  float ax = 0.f, ay = 0.f;
  int scur = (int)(list[beg] >> 24);
  int i = beg;
  for (; i + 4 <= end; i += 4) {
    unsigned u0 = list[i], u1 = list[i+1], u2 = list[i+2], u3 = list[i+3];
    float2 v0 = *(const float2*)(x + (size_t)(u0 & 0xffffffu)*DD + d0);
    float2 v1 = *(const float2*)(x + (size_t)(u1 & 0xffffffu)*DD + d0);
    float2 v2 = *(const float2*)(x + (size_t)(u2 & 0xffffffu)*DD + d0);
    float2 v3 = *(const float2*)(x + (size_t)(u3 & 0xffffffu)*DD + d0);
    int s0 = u0 >> 24, s1 = u1 >> 24, s2 = u2 >> 24, s3 = u3 >> 24;
    if (s0 != scur) { atomicAdd(&gsum[scur*DD + d0], ax); atomicAdd(&gsum[scur*DD + d0 + 1], ay); scur = s0; ax = 0.f; ay = 0.f; }
    ax += v0.x; ay += v0.y;
    if (s1 != scur) { atomicAdd(&gsum[scur*DD + d0], ax); atomicAdd(&gsum[scur*DD + d0 + 1], ay); scur = s1; ax = 0.f; ay = 0.f; }
    ax += v1.x; ay += v1.y;
    if (s2 != scur) { atomicAdd(&gsum[scur*DD + d0], ax); atomicAdd(&gsum[scur*DD + d0 + 1], ay); scur = s2; ax = 0.f; ay = 0.f; }
    ax += v2.x; ay += v2.y;
    if (s3 != scur) { atomicAdd(&gsum[scur*DD + d0], ax); atomicAdd(&gsum[scur*DD + d0 + 1], ay); scur = s3; ax = 0.f; ay = 0.f; }
    ax += v3.x; ay += v3.y;
  }
  for (; i < end; ++i) {
    unsigned u = list[i];
    float2 v = *(const float2*)(x + (size_t)(u & 0xffffffu)*DD + d0);
    int s = u >> 24;
    if (s != scur) { atomicAdd(&gsum[scur*DD + d0], ax); atomicAdd(&gsum[scur*DD + d0 + 1], ay); scur = s; ax = 0.f; ay = 0.f; }
    ax += v.x; ay += v.y;
  }
  atomicAdd(&gsum[scur*DD + d0],     ax);
  atomicAdd(&gsum[scur*DD + d0 + 1], ay);
}

// ================= attention: parallel (1024 threads, 1 block) =============
__global__ __launch_bounds__(1024) void attn_kernel(
    const float* __restrict__ g_sum, const int* __restrict__ row2,
    const float* __restrict__ w1, const float* __restrict__ b1,
    const float* __restrict__ w2, float* __restrict__ subst_attn)
{
  __shared__ float smean[SS*130];
  __shared__ float sw1[8192];
  __shared__ float sc[SS];
  int t = threadIdx.x;
  for (int i = t; i < SS*DD; i += 1024) {
    int s = i >> 7, d = i & 127;
    float c = fmaxf((float)(row2[s+1] - row2[s]), 1.0f);
    smean[s*130 + d] = g_sum[i] / c;
  }
  for (int i = t; i < 8192; i += 1024) sw1[i] = w1[i];
  __syncthreads();

  int s = t >> 4, jq = t & 15;
  float a0 = 0, a1 = 0, a2 = 0, a3 = 0;
  #pragma unroll 4
  for (int d = 0; d < 128; ++d) {
    float m = smean[s*130 + d];
    a0 += m * sw1[d*64 + jq     ];
    a1 += m * sw1[d*64 + jq + 16];
    a2 += m * sw1[d*64 + jq + 32];
    a3 += m * sw1[d*64 + jq + 48];
  }
  float acc = tanhf(a0 + b1[jq     ]) * w2[jq     ]
            + tanhf(a1 + b1[jq + 16]) * w2[jq + 16]
            + tanhf(a2 + b1[jq + 32]) * w2[jq + 32]
            + tanhf(a3 + b1[jq + 48]) * w2[jq + 48];
  acc += __shfl_xor(acc, 1, 64);
  acc += __shfl_xor(acc, 2, 64);
  acc += __shfl_xor(acc, 4, 64);
  acc += __shfl_xor(acc, 8, 64);
  if (jq == 0) sc[s] = acc;
  __syncthreads();
  if (t < 64) {
    float score = sc[t];
    float m = -1e30f;
    for (int i = 0; i < SS; ++i) m = fmaxf(m, sc[i]);
    float e = expf(score - m);
    float sum = 0.0f;
    for (int i = 0; i < SS; ++i) sum += expf(sc[i] - m);
    subst_attn[t] = e / sum;
  }
}

// ================= edge bucketing -> CSR (no global atomics) ===============
__global__ __launch_bounds__(256) void ehist_kernel(const int* __restrict__ dst, int* __restrict__ ehist)
{
  __shared__ int h[EBK];
  int t = threadIdx.x, b = blockIdx.x;
  if (t < EBK) h[t] = 0;
  __syncthreads();
  #pragma unroll
  for (int ii = 0; ii < 8; ++ii) {
    int e = b*2048 + ii*256 + t;
    if (e < EE) atomicAdd(&h[dst[e] >> 9], 1);
  }
  __syncthreads();
  if (t < EBK) ehist[t*EHS + b] = h[t];
}

__global__ __launch_bounds__(1024) void eoffs_kernel(const int* __restrict__ ehist, int* __restrict__ eboff, int* __restrict__ etots)
{
  __shared__ int sh[1024];
  int s = blockIdx.x, t = threadIdx.x;
  int v = (t < NBE) ? ehist[s*EHS + t] : 0;
  sh[t] = v;
  __syncthreads();
  for (int off = 1; off < 1024; off <<= 1) {
    int u = (t >= off) ? sh[t - off] : 0;
    __syncthreads();
    sh[t] += u;
    __syncthreads();
  }
  if (t < NBE) eboff[s*EHS + t] = sh[t] - v;
  if (t == 1023) etots[s] = sh[1023];
}

__global__ __launch_bounds__(256) void ebase_kernel(const int* __restrict__ etots, int* __restrict__ ebase)
{
  __shared__ int sh[256];
  int t = threadIdx.x;
  int v = (t < EBK) ? etots[t] : 0;
  sh[t] = v;
  __syncthreads();
  for (int off = 1; off < 256; off <<= 1) {
    int u = (t >= off) ? sh[t - off] : 0;
    __syncthreads();
    sh[t] += u;
    __syncthreads();
  }
  if (t < EBK) ebase[t] = sh[t] - v;
  if (t == EBK-1) ebase[EBK] = sh[t];   // = EE
}

// packed entry: (dlocal 9b << 17) | src 17b
__global__ __launch_bounds__(256) void escat_kernel(
    const int* __restrict__ src, const int* __restrict__ dst,
    const int* __restrict__ ebase, const int* __restrict__ eboff,
    unsigned* __restrict__ epk)
{
  __shared__ int h[EBK];
  int t = threadIdx.x, b = blockIdx.x;
  if (t < EBK) h[t] = 0;
  __syncthreads();
  #pragma unroll
  for (int ii = 0; ii < 8; ++ii) {
    int e = b*2048 + ii*256 + t;
    if (e < EE) {
      int d = dst[e];
      int k = d >> 9;
      int lr = atomicAdd(&h[k], 1);
      int pos = ebase[k] + eboff[k*EHS + b] + lr;
      epk[pos] = ((unsigned)(d & 511) << 17) | (unsigned)src[e];
    }
  }
}

// one block per bucket: deg/row_off/dinv + coalesced CSR fill
__global__ __launch_bounds__(1024) void csr_build(
    const int* __restrict__ ebase, const unsigned* __restrict__ epk,
    int* __restrict__ row_off, float* __restrict__ dinv, int* __restrict__ csr_src)
{
  __shared__ int scnt[512];
  __shared__ int sh[512];
  __shared__ int cur[512];
  int b = blockIdx.x, t = threadIdx.x;
  int base = ebase[b], cnt_b = ebase[b+1] - base;
  if (t < 512) scnt[t] = 0;
  __syncthreads();
  for (int i = t; i < cnt_b; i += 1024)
    atomicAdd(&scnt[epk[base + i] >> 17], 1);
  __syncthreads();
  int orig = (t < 512) ? scnt[t] : 0;
  if (t < 512) sh[t] = orig;
  __syncthreads();
  for (int off = 1; off < 512; off <<= 1) {
    int u = (t < 512 && t >= off) ? sh[t - off] : 0;
    __syncthreads();
    if (t < 512) sh[t] += u;
    __syncthreads();
  }
  if (t < 512) {
    int excl = sh[t] - orig;
    int n = b*512 + t;
    if (n < NN) {
      row_off[n] = base + excl;
      dinv[n] = rsqrtf((float)(orig + 1));
    }
    cur[t] = excl;
  }
  if (b == EBK-1 && t == 0) row_off[NN] = EE;
  __syncthreads();
  for (int i = t; i < cnt_b; i += 1024) {
    unsigned en = epk[base + i];
    int dl = en >> 17;
    int pos = atomicAdd(&cur[dl], 1);
    csr_src[base + pos] = (int)(en & 0x1FFFFu);
  }
}

// ================= pack x (fp32) -> bf16x2 row-major =================
__global__ __launch_bounds__(256) void packx_kernel(const float* __restrict__ x, unsigned* __restrict__ x16)
{
  int q = blockIdx.x*256 + threadIdx.x;   // uint4 index
  const float4* xf = (const float4*)x;
  float4 f0 = xf[q*2], f1 = xf[q*2+1];
  uint4 pk;
  pk.x = pack2bf(f0.x, f0.y);
  pk.y = pack2bf(f0.z, f0.w);
  pk.z = pack2bf(f1.x, f1.y);
  pk.w = pack2bf(f1.z, f1.w);
  *(uint4*)(x16 + (size_t)q*4) = pk;
}

// ================= pack W -> bf16x2 [col][kpair] =================
__global__ __launch_bounds__(256) void packw_kernel(const float* __restrict__ W, unsigned* __restrict__ W16)
{
  int q = blockIdx.x*256 + threadIdx.x;   // 0..8191
  int c = q & 127, kp = q >> 7;
  float f0 = W[(size_t)(2*kp  )*128 + c];
  float f1 = W[(size_t)(2*kp+1)*128 + c];
  W16[c*64 + kp] = pack2bf(f0, f1);
}

// ================= layer-0 GEMM (bf16 MFMA) with attn rank-1 ==============
__global__ __launch_bounds__(256) void gemm16_kernel(
    const unsigned* __restrict__ A16, const unsigned* __restrict__ W16,
    unsigned* __restrict__ out,
    const int* __restrict__ sid, const float* __restrict__ sattn,
    const float* __restrict__ wextra)
{
  __shared__ unsigned lds[16384];
  __shared__ float sAttn[128];
  __shared__ float sExtra[128];
  int tid = threadIdx.x;
  int lane = tid & 63;
  int row0 = blockIdx.x * 128;

  if (tid < 128) {
    int n = row0 + tid;
    sAttn[tid]  = (n < NN) ? sattn[sid[n]] : 0.0f;
    sExtra[tid] = wextra[tid];
  }

  #pragma unroll
  for (int p = 0; p < 8; ++p) {
    int q  = tid + 256*p;
    int r  = q >> 4;
    int ch = q & 15;
    int n = row0 + r;
    uint4 v = make_uint4(0u,0u,0u,0u);
    if (n < NN) v = *(const uint4*)(A16 + (size_t)n*64 + ch*4);
    int idx = (r*64 + ch*4) ^ ((r & 7) << 2);
    *(uint4*)&lds[idx] = v;
  }
  {
    const uint4* w4 = (const uint4*)W16;
    #pragma unroll
    for (int p = 0; p < 8; ++p) {
      int ch = tid + 256*p;
      int base = ch*4;
      int c = base >> 6;
      int idx = 8192 + (base ^ ((c & 7) << 2));
      *(uint4*)&lds[idx] = w4[ch];
    }
  }
  __syncthreads();

  int w = tid >> 6;
  int wrow = w * 32;
  int swz = (lane & 7) << 2;
  int kgrp = (lane >> 4) * 4;

  f32x4 acc0[8], acc1[8];
  #pragma unroll
  for (int j = 0; j < 8; ++j) { acc0[j] = (f32x4){0,0,0,0}; acc1[j] = (f32x4){0,0,0,0}; }

  #pragma unroll
  for (int kk = 0; kk < 4; ++kk) {
    int kbase = kk*16 + kgrp;
    int rowA0 = wrow + (lane & 15);
    int rowA1 = wrow + 16 + (lane & 15);
    uint4 avu0 = *(const uint4*)&lds[(rowA0*64 + kbase) ^ swz];
    uint4 avu1 = *(const uint4*)&lds[(rowA1*64 + kbase) ^ swz];
    s16x8 a0 = as_s16x8(avu0);
    s16x8 a1 = as_s16x8(avu1);
    #pragma unroll
    for (int j = 0; j < 8; ++j) {
      int col = j*16 + (lane & 15);
      uint4 bvu = *(const uint4*)&lds[8192 + ((col*64 + kbase) ^ swz)];
      s16x8 bfr = as_s16x8(bvu);
      acc0[j] = __builtin_amdgcn_mfma_f32_16x16x32_bf16(a0, bfr, acc0[j], 0, 0, 0);
      acc1[j] = __builtin_amdgcn_mfma_f32_16x16x32_bf16(a1, bfr, acc1[j], 0, 0, 0);
    }
  }
  __syncthreads();

  #pragma unroll
  for (int i2 = 0; i2 < 2; ++i2) {
    #pragma unroll
    for (int j = 0; j < 8; ++j) {
      f32x4 v = i2 ? acc1[j] : acc0[j];
      #pragma unroll
      for (int reg = 0; reg < 4; ++reg) {
        float own = v[reg];
        int r  = wrow + i2*16 + (lane >> 4)*4 + reg;
        int col = j*16 + (lane & 15);
        own += sAttn[r] * sExtra[col];
        float part = __shfl_xor(own, 1, 64);
        if ((lane & 1) == 0) {
          int cp = j*8 + ((lane & 15) >> 1);
          lds[r*68 + cp] = pack2bf(own, part);
        }
      }
    }
  }
  __syncthreads();

  #pragma unroll
  for (int p = 0; p < 8; ++p) {
    int q  = tid + 256*p;
    int r  = q >> 4;
    int ch = q & 15;
    int n = row0 + r;
    if (n < NN) {
      uint4 v = *(const uint4*)&lds[r*68 + ch*4];
      *(uint4*)(out + (size_t)n*64 + ch*4) = v;
    }
  }
}

// ================= FUSED gather(L)+BN/ELU + GEMM(W_{L+1}) ==================
// 512 threads: 8 waves x 16 nodes gather -> swizzled LDS A-tile -> MFMA -> out
__global__ __launch_bounds__(512) void fusedgg_kernel(
    const unsigned* __restrict__ hw, const int* __restrict__ row_off,
    const int* __restrict__ csr_src, const float* __restrict__ dinv,
    const float* __restrict__ bias,
    const float* __restrict__ gma, const float* __restrict__ bta,
    const float* __restrict__ rmn, const float* __restrict__ rvr,
    const unsigned* __restrict__ W16, unsigned* __restrict__ out)
{
  __shared__ unsigned lds[16384];   // sA 0..8191 | sW 8192..16383 | C reuses 0..8703
  int tid = threadIdx.x;
  int wid = tid >> 6;               // 0..7
  int lane = tid & 63;
  int row0 = blockIdx.x * 128;

  // stage W (independent of gather)
  {
    const uint4* w4 = (const uint4*)W16;
    #pragma unroll
    for (int p = 0; p < 4; ++p) {
      int ch = tid + 512*p;         // 0..2047
      int base = ch*4;
      int c = base >> 6;
      int idx = 8192 + (base ^ ((c & 7) << 2));
      *(uint4*)&lds[idx] = w4[ch];
    }
  }

  // hoisted per-lane BN constants (cols j0, j0+1)
  int j0 = lane * 2;
  float iv0 = rsqrtf(rvr[j0]   + 1e-5f);
  float iv1 = rsqrtf(rvr[j0+1] + 1e-5f);
  float g0 = gma[j0], g1 = gma[j0+1];
  float m0 = rmn[j0], m1 = rmn[j0+1];
  float t0v = bta[j0], t1v = bta[j0+1];
  float bb0 = bias[j0], bb1 = bias[j0+1];

  // gather phase: 8 iterations x 2 nodes per wave
  for (int it = 0; it < 8; ++it) {
    int n0 = row0 + wid*16 + it*2;
    if (n0 < NN) {
      n0 = __builtin_amdgcn_readfirstlane(n0);
      int n1 = n0 + 1;
      float di0 = dinv[n0], di1 = dinv[n1];
      unsigned su0 = hw[(size_t)n0*64 + lane];
      unsigned su1 = hw[(size_t)n1*64 + lane];
      float ax0 = bf_lo(su0)*di0*di0, ay0 = bf_hi(su0)*di0*di0;
      float ax1 = bf_lo(su1)*di1*di1, ay1 = bf_hi(su1)*di1*di1;

      int b0 = __builtin_amdgcn_readfirstlane(row_off[n0]);
      int e0 = __builtin_amdgcn_readfirstlane(row_off[n0+1]);
      int e1 = __builtin_amdgcn_readfirstlane(row_off[n1+1]);
      int i0 = b0, i1 = e0;

      for (; i0 + 4 <= e0 && i1 + 4 <= e1; i0 += 4, i1 += 4) {
        int s00 = csr_src[i0+0], s01 = csr_src[i0+1], s02 = csr_src[i0+2], s03 = csr_src[i0+3];
        int s10 = csr_src[i1+0], s11 = csr_src[i1+1], s12 = csr_src[i1+2], s13 = csr_src[i1+3];
        unsigned u00 = hw[(size_t)s00*64 + lane];
        unsigned u01 = hw[(size_t)s01*64 + lane];
        unsigned u02 = hw[(size_t)s02*64 + lane];
        unsigned u03 = hw[(size_t)s03*64 + lane];
        unsigned u10 = hw[(size_t)s10*64 + lane];
        unsigned u11 = hw[(size_t)s11*64 + lane];
        unsigned u12 = hw[(size_t)s12*64 + lane];
        unsigned u13 = hw[(size_t)s13*64 + lane];
        float c00 = dinv[s00]*di0, c01 = dinv[s01]*di0, c02 = dinv[s02]*di0, c03 = dinv[s03]*di0;
        float c10 = dinv[s10]*di1, c11 = dinv[s11]*di1, c12 = dinv[s12]*di1, c13 = dinv[s13]*di1;
        ax0 += bf_lo(u00)*c00 + bf_lo(u01)*c01 + bf_lo(u02)*c02 + bf_lo(u03)*c03;
        ay0 += bf_hi(u00)*c00 + bf_hi(u01)*c01 + bf_hi(u02)*c02 + bf_hi(u03)*c03;
        ax1 += bf_lo(u10)*c10 + bf_lo(u11)*c11 + bf_lo(u12)*c12 + bf_lo(u13)*c13;
        ay1 += bf_hi(u10)*c10 + bf_hi(u11)*c11 + bf_hi(u12)*c12 + bf_hi(u13)*c13;
      }
      for (; i0 + 4 <= e0; i0 += 4) {
        int s0 = csr_src[i0+0], s1 = csr_src[i0+1], s2 = csr_src[i0+2], s3 = csr_src[i0+3];
        unsigned u0 = hw[(size_t)s0*64 + lane];
        unsigned u1 = hw[(size_t)s1*64 + lane];
        unsigned u2 = hw[(size_t)s2*64 + lane];
        unsigned u3 = hw[(size_t)s3*64 + lane];
        float c0 = dinv[s0]*di0, c1 = dinv[s1]*di0, c2 = dinv[s2]*di0, c3 = dinv[s3]*di0;
        ax0 += bf_lo(u0)*c0 + bf_lo(u1)*c1 + bf_lo(u2)*c2 + bf_lo(u3)*c3;
        ay0 += bf_hi(u0)*c0 + bf_hi(u1)*c1 + bf_hi(u2)*c2 + bf_hi(u3)*c3;
      }
      for (; i1 + 4 <= e1; i1 += 4) {
        int s0 = csr_src[i1+0], s1 = csr_src[i1+1], s2 = csr_src[i1+2], s3 = csr_src[i1+3];
        unsigned u0 = hw[(size_t)s0*64 + lane];
        unsigned u1 = hw[(size_t)s1*64 + lane];
        unsigned u2 = hw[(size_t)s2*64 + lane];
        unsigned u3 = hw[(size_t)s3*64 + lane];
        float c0 = dinv[s0]*di1, c1 = dinv[s1]*di1, c2 = dinv[s2]*di1, c3 = dinv[s3]*di1;
        ax1 += bf_lo(u0)*c0 + bf_lo(u1)*c1 + bf_lo(u2)*c2 + bf_lo(u3)*c3;
        ay1 += bf_hi(u0)*c0 + bf_hi(u1)*c1 + bf_hi(u2)*c2 + bf_hi(u3)*c3;
      }
      for (; i0 < e0; ++i0) {
        int s = csr_src[i0];
        float c = dinv[s]*di0;
        unsigned u = hw[(size_t)s*64 + lane];
        ax0 += bf_lo(u)*c; ay0 += bf_hi(u)*c;
      }
      for (; i1 < e1; ++i1) {
        int s = csr_src[i1];
        float c = dinv[s]*di1;
        unsigned u = hw[(size_t)s*64 + lane];
        ax1 += bf_lo(u)*c; ay1 += bf_hi(u)*c;
      }

      float y00 = (ax0 + bb0 - m0) * iv0 * g0 + t0v;
      float y01 = (ay0 + bb1 - m1) * iv1 * g1 + t1v;
      float y10 = (ax1 + bb0 - m0) * iv0 * g0 + t0v;
      float y11 = (ay1 + bb1 - m1) * iv1 * g1 + t1v;
      // ELU (fused layers are always 0..2)
      y00 = (y00 > 0.0f) ? y00 : expm1f(y00);
      y01 = (y01 > 0.0f) ? y01 : expm1f(y01);
      y10 = (y10 > 0.0f) ? y10 : expm1f(y10);
      y11 = (y11 > 0.0f) ? y11 : expm1f(y11);

      int r0 = n0 - row0, r1 = r0 + 1;
      lds[(r0*64 + lane) ^ ((r0 & 7) << 2)] = pack2bf(y00, y01);
      lds[(r1*64 + lane) ^ ((r1 & 7) << 2)] = pack2bf(y10, y11);
    }
  }
  __syncthreads();

  // gemm phase: 8 waves x 16 rows each
  int wrow = wid * 16;
  int swz = (lane & 7) << 2;
  int kgrp = (lane >> 4) * 4;

  f32x4 acc0[8];
  #pragma unroll
  for (int j = 0; j < 8; ++j) acc0[j] = (f32x4){0,0,0,0};

  #pragma unroll
  for (int kk = 0; kk < 4; ++kk) {
    int kbase = kk*16 + kgrp;
    int rowA0 = wrow + (lane & 15);
    uint4 avu0 = *(const uint4*)&lds[(rowA0*64 + kbase) ^ swz];
    s16x8 a0 = as_s16x8(avu0);
    #pragma unroll
    for (int j = 0; j < 8; ++j) {
      int col = j*16 + (lane & 15);
      uint4 bvu = *(const uint4*)&lds[8192 + ((col*64 + kbase) ^ swz)];
      s16x8 bfr = as_s16x8(bvu);
      acc0[j] = __builtin_amdgcn_mfma_f32_16x16x32_bf16(a0, bfr, acc0[j], 0, 0, 0);
    }
  }
  __syncthreads();

  #pragma unroll
  for (int j = 0; j < 8; ++j) {
    #pragma unroll
    for (int reg = 0; reg < 4; ++reg) {
      float own = acc0[j][reg];
      float part = __shfl_xor(own, 1, 64);
      if ((lane & 1) == 0) {
        int r  = wrow + (lane >> 4)*4 + reg;
        int cp = j*8 + ((lane & 15) >> 1);
        lds[r*68 + cp] = pack2bf(own, part);
      }
    }
  }
  __syncthreads();

  #pragma unroll
  for (int p = 0; p < 4; ++p) {
    int q  = tid + 512*p;      // 0..2047
    int r  = q >> 4;
    int ch = q & 15;
    int n = row0 + r;
    if (n < NN) {
      uint4 v = *(const uint4*)&lds[r*68 + ch*4];
      *(uint4*)(out + (size_t)n*64 + ch*4) = v;
    }
  }
}

// ================= final gather (L3, ReLU) =================
__global__ __launch_bounds__(256) void gather_kernel(
    const unsigned* __restrict__ hw, const int* __restrict__ row_off,
    const int* __restrict__ csr_src,
    const float* __restrict__ dinv, const float* __restrict__ bias,
    const float* __restrict__ gma, const float* __restrict__ bta,
    const float* __restrict__ rmn, const float* __restrict__ rvr,
    unsigned* __restrict__ out)
{
  int w = (blockIdx.x*256 + threadIdx.x) >> 6;
  int lane = threadIdx.x & 63;
  int n0 = w * 2;
  if (n0 >= NN) return;
  n0 = __builtin_amdgcn_readfirstlane(n0);
  int n1 = n0 + 1;
  int j0 = lane * 2;

  float di0 = dinv[n0], di1 = dinv[n1];
  unsigned su0 = hw[(size_t)n0*64 + lane];
  unsigned su1 = hw[(size_t)n1*64 + lane];
  float ax0 = bf_lo(su0)*di0*di0, ay0 = bf_hi(su0)*di0*di0;
  float ax1 = bf_lo(su1)*di1*di1, ay1 = bf_hi(su1)*di1*di1;

  int b0 = __builtin_amdgcn_readfirstlane(row_off[n0]);
  int e0 = __builtin_amdgcn_readfirstlane(row_off[n0+1]);
  int e1 = __builtin_amdgcn_readfirstlane(row_off[n1+1]);
  int i0 = b0, i1 = e0;

  for (; i0 + 4 <= e0 && i1 + 4 <= e1; i0 += 4, i1 += 4) {
    int s00 = csr_src[i0+0], s01 = csr_src[i0+1], s02 = csr_src[i0+2], s03 = csr_src[i0+3];
    int s10 = csr_src[i1+0], s11 = csr_src[i1+1], s12 = csr_src[i1+2], s13 = csr_src[i1+3];
    unsigned u00 = hw[(size_t)s00*64 + lane];
    unsigned u01 = hw[(size_t)s01*64 + lane];
    unsigned u02 = hw[(size_t)s02*64 + lane];
    unsigned u03 = hw[(size_t)s03*64 + lane];
    unsigned u10 = hw[(size_t)s10*64 + lane];
    unsigned u11 = hw[(size_t)s11*64 + lane];
    unsigned u12 = hw[(size_t)s12*64 + lane];
    unsigned u13 = hw[(size_t)s13*64 + lane];
    float c00 = dinv[s00]*di0, c01 = dinv[s01]*di0, c02 = dinv[s02]*di0, c03 = dinv[s03]*di0;
    float c10 = dinv[s10]*di1, c11 = dinv[s11]*di1, c12 = dinv[s12]*di1, c13 = dinv[s13]*di1;
    ax0 += bf_lo(u00)*c00 + bf_lo(u01)*c01 + bf_lo(u02)*c02 + bf_lo(u03)*c03;
    ay0 += bf_hi(u00)*c00 + bf_hi(u01)*c01 + bf_hi(u02)*c02 + bf_hi(u03)*c03;
    ax1 += bf_lo(u10)*c10 + bf_lo(u11)*c11 + bf_lo(u12)*c12 + bf_lo(u13)*c13;
    ay1 += bf_hi(u10)*c10 + bf_hi(u11)*c11 + bf_hi(u12)*c12 + bf_hi(u13)*c13;
  }
  for (; i0 + 4 <= e0; i0 += 4) {
    int s0 = csr_src[i0+0], s1 = csr_src[i0+1], s2 = csr_src[i0+2], s3 = csr_src[i0+3];
    unsigned u0 = hw[(size_t)s0*64 + lane];
    unsigned u1 = hw[(size_t)s1*64 + lane];
    unsigned u2 = hw[(size_t)s2*64 + lane];
    unsigned u3 = hw[(size_t)s3*64 + lane];
    float c0 = dinv[s0]*di0, c1 = dinv[s1]*di0, c2 = dinv[s2]*di0, c3 = dinv[s3]*di0;
    ax0 += bf_lo(u0)*c0 + bf_lo(u1)*c1 + bf_lo(u2)*c2 + bf_lo(u3)*c3;
    ay0 += bf_hi(u0)*c0 + bf_hi(u1)*c1 + bf_hi(u2)*c2 + bf_hi(u3)*c3;
  }
  for (; i1 + 4 <= e1; i1 += 4) {
    int s0 = csr_src[i1+0], s1 = csr_src[i1+1], s2 = csr_src[i1+2], s3 = csr_src[i1+3];
    unsigned u0 = hw[(size_t)s0*64 + lane];
    unsigned u1 = hw[(size_t)s1*64 + lane];
    unsigned u2 = hw[(size_t)s2*64 + lane];
    unsigned u3 = hw[(size_t)s3*64 + lane];
    float c0 = dinv[s0]*di1, c1 = dinv[s1]*di1, c2 = dinv[s2]*di1, c3 = dinv[s3]*di1;
    ax1 += bf_lo(u0)*c0 + bf_lo(u1)*c1 + bf_lo(u2)*c2 + bf_lo(u3)*c3;
    ay1 += bf_hi(u0)*c0 + bf_hi(u1)*c1 + bf_hi(u2)*c2 + bf_hi(u3)*c3;
  }
  for (; i0 < e0; ++i0) {
    int s = csr_src[i0];
    float c = dinv[s]*di0;
    unsigned u = hw[(size_t)s*64 + lane];
    ax0 += bf_lo(u)*c; ay0 += bf_hi(u)*c;
  }
  for (; i1 < e1; ++i1) {
    int s = csr_src[i1];
    float c = dinv[s]*di1;
    unsigned u = hw[(size_t)s*64 + lane];
    ax1 += bf_lo(u)*c; ay1 += bf_hi(u)*c;
  }

  float iv0 = rsqrtf(rvr[j0]   + 1e-5f);
  float iv1 = rsqrtf(rvr[j0+1] + 1e-5f);
  float g0 = gma[j0], g1 = gma[j0+1];
  float m0 = rmn[j0], m1 = rmn[j0+1];
  float t0 = bta[j0], t1 = bta[j0+1];
  float bb0 = bias[j0], bb1 = bias[j0+1];

  float y00 = fmaxf((ax0 + bb0 - m0) * iv0 * g0 + t0, 0.0f);
  float y01 = fmaxf((ay0 + bb1 - m1) * iv1 * g1 + t1, 0.0f);
  float y10 = fmaxf((ax1 + bb0 - m0) * iv0 * g0 + t0, 0.0f);
  float y11 = fmaxf((ay1 + bb1 - m1) * iv1 * g1 + t1, 0.0f);
  out[(size_t)n0*64 + lane] = pack2bf(y00, y01);
  out[(size_t)n1*64 + lane] = pack2bf(y10, y11);
}

// ================= graph starts / pool / head =================
__global__ __launch_bounds__(256) void gstart_kernel(const int* __restrict__ batch, int* __restrict__ start)
{
  int n = blockIdx.x*256 + threadIdx.x;
  if (n >= NN) return;
  int b  = batch[n];
  int bp = (n == 0) ? -1 : batch[n-1];
  for (int g = bp + 1; g <= b; ++g) start[g] = n;
  if (n == NN-1) {
    for (int g = b + 1; g <= GG; ++g) start[g] = NN;
  }
}

__global__ __launch_bounds__(256) void pool_kernel(
    const unsigned* __restrict__ h16, const int* __restrict__ batch, float* __restrict__ pooled)
{
  int wave = (blockIdx.x*256 + threadIdx.x) >> 6;
  int lane = threadIdx.x & 63;
  const int CH = 64;
  int beg = wave * CH;
  if (beg >= NN) return;
  int end = min(beg + CH, NN);
  int j0 = lane * 2;
  float ax = 0.f, ay = 0.f;
  int gcur = batch[beg];
  for (int n = beg; n < end; ++n) {
    int g = batch[n];
    if (g != gcur) {
      atomicAdd(&pooled[(size_t)gcur*128 + j0],     ax);
      atomicAdd(&pooled[(size_t)gcur*128 + j0 + 1], ay);
      ax = 0.f; ay = 0.f; gcur = g;
    }
    unsigned u = h16[(size_t)n*64 + lane];
    ax += bf_lo(u); ay += bf_hi(u);
  }
  atomicAdd(&pooled[(size_t)gcur*128 + j0],     ax);
  atomicAdd(&pooled[(size_t)gcur*128 + j0 + 1], ay);
}

__global__ __launch_bounds__(64) void head_kernel(
    const float* __restrict__ pooled, const int* __restrict__ start,
    const float* __restrict__ w1, const float* __restrict__ b1,
    const float* __restrict__ w2, const float* __restrict__ b2,
    float* __restrict__ out)
{
  __shared__ float p[128];
  int g = blockIdx.x;
  int t = threadIdx.x;
  float cnt = fmaxf((float)(start[g+1] - start[g]), 1.0f);
  p[t]      = pooled[(size_t)g*128 + t]      / cnt;
  p[t + 64] = pooled[(size_t)g*128 + t + 64] / cnt;
  __syncthreads();
  float a = 0.f;
  #pragma unroll 4
  for (int d = 0; d < 128; ++d) a += p[d] * w1[d*64 + t];
  float z = a + b1[t];
  z = (z > 0.f) ? z : expm1f(z);
  float v = z * w2[t];
  #pragma unroll
  for (int off = 32; off > 0; off >>= 1) v += __shfl_down(v, off, 64);
  if (t == 0) out[g] = v + b2[0];
}

extern "C" void kernel_launch(void* const* d_in, const int* in_sizes, int n_in,
                              void* d_out, int out_size, void* d_ws, size_t ws_size,
                              hipStream_t stream)
{
  const float* x        = (const float*)d_in[0];
  const int*   eidx     = (const int*)d_in[1];
  const int*   sid      = (const int*)d_in[2];
  const int*   batch    = (const int*)d_in[3];
  const float* attn_w1  = (const float*)d_in[4];
  const float* attn_b1  = (const float*)d_in[5];
  const float* attn_w2  = (const float*)d_in[6];
  const float* conv_w[4] = {(const float*)d_in[7], (const float*)d_in[9],
                            (const float*)d_in[11], (const float*)d_in[13]};
  const float* conv_b[4] = {(const float*)d_in[8], (const float*)d_in[10],
                            (const float*)d_in[12], (const float*)d_in[14]};
  const float* bn_gamma = (const float*)d_in[15];
  const float* bn_beta  = (const float*)d_in[16];
  const float* bn_rmean = (const float*)d_in[17];
  const float* bn_rvar  = (const float*)d_in[18];
  const float* head_w1  = (const float*)d_in[19];
  const float* head_b1  = (const float*)d_in[20];
  const float* head_w2  = (const float*)d_in[21];
  const float* head_b2  = (const float*)d_in[22];
  float* out = (float*)d_out;

  char* ws = (char*)d_ws;
  unsigned* buf0  = (unsigned*)(ws + OFF_HW);
  unsigned* buf1  = (unsigned*)(ws + OFF_H);
  unsigned* x16   = (unsigned*)(ws + OFF_X16);
  int*   csr_src  = (int*)  (ws + OFF_CSRS);
  int*   row_off  = (int*)  (ws + OFF_ROW);
  float* dinv     = (float*)(ws + OFF_DINV);
  float* sattn    = (float*)(ws + OFF_SATT);
  int*   gstart   = (int*)  (ws + OFF_GST);
  int*   bhist    = (int*)  (ws + OFF_BH);
  int*   boff2    = (int*)  (ws + OFF_BO);
  int*   tots     = (int*)  (ws + OFF_TOT);
  int*   row2     = (int*)  (ws + OFF_ROW2);
  unsigned* list  = (unsigned*)(ws + OFF_LIST);
  unsigned* w16   = (unsigned*)(ws + OFF_W16);
  int*   ehist    = (int*)  (ws + OFF_EH);
  int*   eboff    = (int*)  (ws + OFF_EB);
  int*   etots    = (int*)  (ws + OFF_ET);
  int*   ebase    = (int*)  (ws + OFF_EBASE);
  unsigned* epk   = (unsigned*)(ws + OFF_EPK);
  float* pooled   = (float*)(ws + OFF_POOL);
  float* gsum     = (float*)(ws + OFF_GSUM);

  const int* e_src = eidx;
  const int* e_dst = eidx + EE;

  hipMemsetAsync(ws + ZERO_BEG, 0, ZERO_BYTES, stream);

  int nb256 = (NN + 255)/256;  // 391

  // substructure attention
  hist_kernel <<<nb256, 256, 0, stream>>>(sid, bhist);
  offs_kernel <<<64, 512, 0, stream>>>(bhist, boff2, tots);
  base_kernel <<<1, 64, 0, stream>>>(tots, row2);
  fill2_kernel<<<nb256, 256, 0, stream>>>(sid, row2, boff2, list);
  subst_sum   <<<1024, 256, 0, stream>>>(list, x, gsum);
  attn_kernel <<<1, 1024, 0, stream>>>(gsum, row2, attn_w1, attn_b1, attn_w2, sattn);

  // CSR via dst bucketing (no global atomics, packed edges)
  ehist_kernel<<<NBE, 256, 0, stream>>>(e_dst, ehist);
  eoffs_kernel<<<EBK, 1024, 0, stream>>>(ehist, eboff, etots);
  ebase_kernel<<<1, 256, 0, stream>>>(etots, ebase);
  escat_kernel<<<NBE, 256, 0, stream>>>(e_src, e_dst, ebase, eboff, epk);
  csr_build   <<<EBK, 1024, 0, stream>>>(ebase, epk, row_off, dinv, csr_src);

  gstart_kernel<<<nb256, 256, 0, stream>>>(batch, gstart);

  // pack inputs to bf16
  packx_kernel<<<(NN*16)/256, 256, 0, stream>>>(x, x16);
  for (int L = 0; L < 4; ++L)
    packw_kernel<<<32, 256, 0, stream>>>(conv_w[L], w16 + (size_t)L*8192);

  int gemm_grid = (NN + 127)/128;        // 782
  int gat_grid  = ((NN/2)*64 + 255)/256; // 12500

  // layer-0 GEMM: x16@W0 + attn -> buf0
  gemm16_kernel<<<gemm_grid, 256, 0, stream>>>(x16, w16, buf0,
      sid, sattn, conv_w[0] + 128*128);

  // fused gather(L)+BN/ELU + GEMM(W_{L+1}), L = 0,1,2
  fusedgg_kernel<<<gemm_grid, 512, 0, stream>>>(buf0, row_off, csr_src, dinv,
      conv_b[0], bn_gamma + 0*HH, bn_beta + 0*HH, bn_rmean + 0*HH, bn_rvar + 0*HH,
      w16 + (size_t)1*8192, buf1);
  fusedgg_kernel<<<gemm_grid, 512, 0, stream>>>(buf1, row_off, csr_src, dinv,
      conv_b[1], bn_gamma + 1*HH, bn_beta + 1*HH, bn_rmean + 1*HH, bn_rvar + 1*HH,
      w16 + (size_t)2*8192, buf0);
  fusedgg_kernel<<<gemm_grid, 512, 0, stream>>>(buf0, row_off, csr_src, dinv,
      conv_b[2], bn_gamma + 2*HH, bn_beta + 2*HH, bn_rmean + 2*HH, bn_rvar + 2*HH,
      w16 + (size_t)3*8192, buf1);

  // final gather (L3, ReLU) -> buf0
  gather_kernel<<<gat_grid, 256, 0, stream>>>(buf1, row_off, csr_src, dinv,
      conv_b[3], bn_gamma + 3*HH, bn_beta + 3*HH, bn_rmean + 3*HH, bn_rvar + 3*HH,
      buf0);

  int pool_waves  = (NN + 63)/64;               // 1563
  int pool_blocks = (pool_waves + 3)/4;         // 391
  pool_kernel<<<pool_blocks, 256, 0, stream>>>(buf0, batch, pooled);
  head_kernel<<<GG, 64, 0, stream>>>(pooled, gstart, head_w1, head_b1, head_w2, head_b2, out);
}

// Round 12
// 512.535 us; speedup vs baseline: 1.1299x; 1.1299x over previous
//
#include <hip/hip_runtime.h>
#include <cmath>

#define NN 100000
#define EE 1600000
#define DD 128
#define HH 128
#define SS 64
#define GG 512

#define NBE 782    // edge blocks of 2048
#define EBK 196    // dst buckets of 512 nodes
#define EHS 800    // ehist row stride

typedef float f32x4 __attribute__((ext_vector_type(4)));
typedef short s16x8 __attribute__((ext_vector_type(8)));

constexpr size_t alignup(size_t x){ return (x + 255) & ~(size_t)255; }
constexpr size_t SZ_P16   = (size_t)NN*64*sizeof(unsigned);       // 25.6MB packed bf16x2
constexpr size_t OFF_HW   = 0;                                     // BUF0
constexpr size_t OFF_H    = alignup(OFF_HW + SZ_P16);              // BUF1
constexpr size_t OFF_X16  = alignup(OFF_H + SZ_P16);              // bf16-packed x
constexpr size_t OFF_CSRS = alignup(OFF_X16 + SZ_P16);
constexpr size_t OFF_ROW  = alignup(OFF_CSRS + (size_t)EE*4);
constexpr size_t OFF_DINV = alignup(OFF_ROW + (size_t)(NN+1)*4);
constexpr size_t OFF_SATT = alignup(OFF_DINV + (size_t)NN*4);
constexpr size_t OFF_GST  = alignup(OFF_SATT + 64*4);             // start[513]
// sid-bucket machinery
constexpr size_t OFF_BH   = alignup(OFF_GST + 513*4);             // bhist [64][400]
constexpr size_t OFF_BO   = alignup(OFF_BH + (size_t)64*400*4);   // boff2 [64][400]
constexpr size_t OFF_TOT  = alignup(OFF_BO + (size_t)64*400*4);   // tots[64]
constexpr size_t OFF_ROW2 = alignup(OFF_TOT + 64*4);              // row2[65]
constexpr size_t OFF_LIST = alignup(OFF_ROW2 + 65*4);             // list[N]
constexpr size_t OFF_W16  = alignup(OFF_LIST + (size_t)NN*4);     // 4 x 8192
// edge-bucket machinery
constexpr size_t OFF_EH   = alignup(OFF_W16 + (size_t)4*8192*4);  // ehist [196][800]
constexpr size_t OFF_EB   = alignup(OFF_EH + (size_t)EBK*EHS*4);  // eboff [196][800]
constexpr size_t OFF_ET   = alignup(OFF_EB + (size_t)EBK*EHS*4);  // etots[196]
constexpr size_t OFF_EBASE= alignup(OFF_ET + EBK*4);              // ebase[197]
constexpr size_t OFF_EPK  = alignup(OFF_EBASE + 200*4);           // packed (dlocal<<17|src) [E]
// ---- zeroed region ----
constexpr size_t OFF_POOL = alignup(OFF_EPK + (size_t)EE*4);
constexpr size_t OFF_GSUM = alignup(OFF_POOL + (size_t)GG*HH*4);  // [8192]
constexpr size_t OFF_END  = alignup(OFF_GSUM + (size_t)SS*DD*4);
constexpr size_t ZERO_BEG   = OFF_POOL;
constexpr size_t ZERO_BYTES = OFF_END - OFF_POOL;

__device__ __forceinline__ unsigned pack2bf(float a, float b){
  unsigned ua = __float_as_uint(a); ua += 0x7fffu + ((ua >> 16) & 1u);
  unsigned ub = __float_as_uint(b); ub += 0x7fffu + ((ub >> 16) & 1u);
  return (ua >> 16) | (ub & 0xffff0000u);
}
__device__ __forceinline__ float bf_lo(unsigned u){ return __uint_as_float(u << 16); }
__device__ __forceinline__ float bf_hi(unsigned u){ return __uint_as_float(u & 0xffff0000u); }
__device__ __forceinline__ s16x8 as_s16x8(uint4 v){ union { uint4 u; s16x8 s; } x; x.u = v; return x.s; }

// ================= sid bucketing (for subst mean) =================
__global__ __launch_bounds__(256) void hist_kernel(const int* __restrict__ sid, int* __restrict__ bhist)
{
  __shared__ int h[64];
  int t = threadIdx.x, b = blockIdx.x;
  if (t < 64) h[t] = 0;
  __syncthreads();
  int n = b*256 + t;
  if (n < NN) atomicAdd(&h[sid[n]], 1);
  __syncthreads();
  if (t < 64) bhist[t*400 + b] = h[t];
}

__global__ __launch_bounds__(512) void offs_kernel(const int* __restrict__ bhist, int* __restrict__ boff2, int* __restrict__ tots)
{
  __shared__ int sh[512];
  int s = blockIdx.x, t = threadIdx.x;
  int v = (t < 391) ? bhist[s*400 + t] : 0;
  sh[t] = v;
  __syncthreads();
  for (int off = 1; off < 512; off <<= 1) {
    int u = (t >= off) ? sh[t - off] : 0;
    __syncthreads();
    sh[t] += u;
    __syncthreads();
  }
  if (t < 391) boff2[s*400 + t] = sh[t] - v;
  if (t == 511) tots[s] = sh[511];
}

__global__ __launch_bounds__(64) void base_kernel(const int* __restrict__ tots, int* __restrict__ row2)
{
  int l = threadIdx.x;
  int v = tots[l];
  int xv = v;
  #pragma unroll
  for (int off = 1; off < 64; off <<= 1) {
    int u = __shfl_up(xv, off, 64);
    if (l >= off) xv += u;
  }
  row2[l] = xv - v;
  if (l == 63) row2[64] = xv;
}

__global__ __launch_bounds__(256) void fill2_kernel(
    const int* __restrict__ sid, const int* __restrict__ row2,
    const int* __restrict__ boff2, unsigned* __restrict__ list)
{
  __shared__ int h[64];
  int t = threadIdx.x, b = blockIdx.x;
  if (t < 64) h[t] = 0;
  __syncthreads();
  int n = b*256 + t;
  if (n < NN) {
    int s = sid[n];
    int lr = atomicAdd(&h[s], 1);
    int pos = row2[s] + boff2[s*400 + b] + lr;
    list[pos] = ((unsigned)s << 24) | (unsigned)n;
  }
}

// reads bf16-packed x16 (half the traffic of fp32 x)
__global__ __launch_bounds__(256) void subst_sum(
    const unsigned* __restrict__ list, const unsigned* __restrict__ x16,
    float* __restrict__ gsum)
{
  int b = blockIdx.x, t = threadIdx.x;
  int lane = t & 63, w = t >> 6;
  const int per = (NN + 1023)/1024;   // 98
  const int q   = (per + 3)/4;        // 25
  int bend = min(b*per + per, NN);
  int beg = b*per + w*q;
  int end = min(bend, beg + q);
  if (beg >= end) return;
  int d0 = lane * 2;
  float ax = 0.f, ay = 0.f;
  int scur = (int)(list[beg] >> 24);
  int i = beg;
  for (; i + 4 <= end; i += 4) {
    unsigned u0 = list[i], u1 = list[i+1], u2 = list[i+2], u3 = list[i+3];
    unsigned w0 = x16[(size_t)(u0 & 0xffffffu)*64 + lane];
    unsigned w1v = x16[(size_t)(u1 & 0xffffffu)*64 + lane];
    unsigned w2v = x16[(size_t)(u2 & 0xffffffu)*64 + lane];
    unsigned w3 = x16[(size_t)(u3 & 0xffffffu)*64 + lane];
    int s0 = u0 >> 24, s1 = u1 >> 24, s2 = u2 >> 24, s3 = u3 >> 24;
    if (s0 != scur) { atomicAdd(&gsum[scur*DD + d0], ax); atomicAdd(&gsum[scur*DD + d0 + 1], ay); scur = s0; ax = 0.f; ay = 0.f; }
    ax += bf_lo(w0); ay += bf_hi(w0);
    if (s1 != scur) { atomicAdd(&gsum[scur*DD + d0], ax); atomicAdd(&gsum[scur*DD + d0 + 1], ay); scur = s1; ax = 0.f; ay = 0.f; }
    ax += bf_lo(w1v); ay += bf_hi(w1v);
    if (s2 != scur) { atomicAdd(&gsum[scur*DD + d0], ax); atomicAdd(&gsum[scur*DD + d0 + 1], ay); scur = s2; ax = 0.f; ay = 0.f; }
    ax += bf_lo(w2v); ay += bf_hi(w2v);
    if (s3 != scur) { atomicAdd(&gsum[scur*DD + d0], ax); atomicAdd(&gsum[scur*DD + d0 + 1], ay); scur = s3; ax = 0.f; ay = 0.f; }
    ax += bf_lo(w3); ay += bf_hi(w3);
  }
  for (; i < end; ++i) {
    unsigned u = list[i];
    unsigned wv = x16[(size_t)(u & 0xffffffu)*64 + lane];
    int s = u >> 24;
    if (s != scur) { atomicAdd(&gsum[scur*DD + d0], ax); atomicAdd(&gsum[scur*DD + d0 + 1], ay); scur = s; ax = 0.f; ay = 0.f; }
    ax += bf_lo(wv); ay += bf_hi(wv);
  }
  atomicAdd(&gsum[scur*DD + d0],     ax);
  atomicAdd(&gsum[scur*DD + d0 + 1], ay);
}

// ================= attention: parallel (1024 threads, 1 block) =============
__global__ __launch_bounds__(1024) void attn_kernel(
    const float* __restrict__ g_sum, const int* __restrict__ row2,
    const float* __restrict__ w1, const float* __restrict__ b1,
    const float* __restrict__ w2, float* __restrict__ subst_attn)
{
  __shared__ float smean[SS*130];
  __shared__ float sw1[8192];
  __shared__ float sc[SS];
  int t = threadIdx.x;
  for (int i = t; i < SS*DD; i += 1024) {
    int s = i >> 7, d = i & 127;
    float c = fmaxf((float)(row2[s+1] - row2[s]), 1.0f);
    smean[s*130 + d] = g_sum[i] / c;
  }
  for (int i = t; i < 8192; i += 1024) sw1[i] = w1[i];
  __syncthreads();

  int s = t >> 4, jq = t & 15;
  float a0 = 0, a1 = 0, a2 = 0, a3 = 0;
  #pragma unroll 4
  for (int d = 0; d < 128; ++d) {
    float m = smean[s*130 + d];
    a0 += m * sw1[d*64 + jq     ];
    a1 += m * sw1[d*64 + jq + 16];
    a2 += m * sw1[d*64 + jq + 32];
    a3 += m * sw1[d*64 + jq + 48];
  }
  float acc = tanhf(a0 + b1[jq     ]) * w2[jq     ]
            + tanhf(a1 + b1[jq + 16]) * w2[jq + 16]
            + tanhf(a2 + b1[jq + 32]) * w2[jq + 32]
            + tanhf(a3 + b1[jq + 48]) * w2[jq + 48];
  acc += __shfl_xor(acc, 1, 64);
  acc += __shfl_xor(acc, 2, 64);
  acc += __shfl_xor(acc, 4, 64);
  acc += __shfl_xor(acc, 8, 64);
  if (jq == 0) sc[s] = acc;
  __syncthreads();
  if (t < 64) {
    float score = sc[t];
    float m = -1e30f;
    for (int i = 0; i < SS; ++i) m = fmaxf(m, sc[i]);
    float e = expf(score - m);
    float sum = 0.0f;
    for (int i = 0; i < SS; ++i) sum += expf(sc[i] - m);
    subst_attn[t] = e / sum;
  }
}

// ================= edge bucketing -> CSR (no global atomics) ===============
__global__ __launch_bounds__(256) void ehist_kernel(const int* __restrict__ dst, int* __restrict__ ehist)
{
  __shared__ int h[EBK];
  int t = threadIdx.x, b = blockIdx.x;
  if (t < EBK) h[t] = 0;
  __syncthreads();
  #pragma unroll
  for (int ii = 0; ii < 8; ++ii) {
    int e = b*2048 + ii*256 + t;
    if (e < EE) atomicAdd(&h[dst[e] >> 9], 1);
  }
  __syncthreads();
  if (t < EBK) ehist[t*EHS + b] = h[t];
}

__global__ __launch_bounds__(1024) void eoffs_kernel(const int* __restrict__ ehist, int* __restrict__ eboff, int* __restrict__ etots)
{
  __shared__ int sh[1024];
  int s = blockIdx.x, t = threadIdx.x;
  int v = (t < NBE) ? ehist[s*EHS + t] : 0;
  sh[t] = v;
  __syncthreads();
  for (int off = 1; off < 1024; off <<= 1) {
    int u = (t >= off) ? sh[t - off] : 0;
    __syncthreads();
    sh[t] += u;
    __syncthreads();
  }
  if (t < NBE) eboff[s*EHS + t] = sh[t] - v;
  if (t == 1023) etots[s] = sh[1023];
}

__global__ __launch_bounds__(256) void ebase_kernel(const int* __restrict__ etots, int* __restrict__ ebase)
{
  __shared__ int sh[256];
  int t = threadIdx.x;
  int v = (t < EBK) ? etots[t] : 0;
  sh[t] = v;
  __syncthreads();
  for (int off = 1; off < 256; off <<= 1) {
    int u = (t >= off) ? sh[t - off] : 0;
    __syncthreads();
    sh[t] += u;
    __syncthreads();
  }
  if (t < EBK) ebase[t] = sh[t] - v;
  if (t == EBK-1) ebase[EBK] = sh[t];   // = EE
}

// packed entry: (dlocal 9b << 17) | src 17b
__global__ __launch_bounds__(256) void escat_kernel(
    const int* __restrict__ src, const int* __restrict__ dst,
    const int* __restrict__ ebase, const int* __restrict__ eboff,
    unsigned* __restrict__ epk)
{
  __shared__ int h[EBK];
  int t = threadIdx.x, b = blockIdx.x;
  if (t < EBK) h[t] = 0;
  __syncthreads();
  #pragma unroll
  for (int ii = 0; ii < 8; ++ii) {
    int e = b*2048 + ii*256 + t;
    if (e < EE) {
      int d = dst[e];
      int k = d >> 9;
      int lr = atomicAdd(&h[k], 1);
      int pos = ebase[k] + eboff[k*EHS + b] + lr;
      epk[pos] = ((unsigned)(d & 511) << 17) | (unsigned)src[e];
    }
  }
}

// one block per bucket: deg/row_off/dinv + coalesced CSR fill
__global__ __launch_bounds__(1024) void csr_build(
    const int* __restrict__ ebase, const unsigned* __restrict__ epk,
    int* __restrict__ row_off, float* __restrict__ dinv, int* __restrict__ csr_src)
{
  __shared__ int scnt[512];
  __shared__ int sh[512];
  __shared__ int cur[512];
  int b = blockIdx.x, t = threadIdx.x;
  int base = ebase[b], cnt_b = ebase[b+1] - base;
  if (t < 512) scnt[t] = 0;
  __syncthreads();
  for (int i = t; i < cnt_b; i += 1024)
    atomicAdd(&scnt[epk[base + i] >> 17], 1);
  __syncthreads();
  int orig = (t < 512) ? scnt[t] : 0;
  if (t < 512) sh[t] = orig;
  __syncthreads();
  for (int off = 1; off < 512; off <<= 1) {
    int u = (t < 512 && t >= off) ? sh[t - off] : 0;
    __syncthreads();
    if (t < 512) sh[t] += u;
    __syncthreads();
  }
  if (t < 512) {
    int excl = sh[t] - orig;
    int n = b*512 + t;
    if (n < NN) {
      row_off[n] = base + excl;
      dinv[n] = rsqrtf((float)(orig + 1));
    }
    cur[t] = excl;
  }
  if (b == EBK-1 && t == 0) row_off[NN] = EE;
  __syncthreads();
  for (int i = t; i < cnt_b; i += 1024) {
    unsigned en = epk[base + i];
    int dl = en >> 17;
    int pos = atomicAdd(&cur[dl], 1);
    csr_src[base + pos] = (int)(en & 0x1FFFFu);
  }
}

// ================= pack x (fp32) -> bf16x2 row-major =================
__global__ __launch_bounds__(256) void packx_kernel(const float* __restrict__ x, unsigned* __restrict__ x16)
{
  int q = blockIdx.x*256 + threadIdx.x;   // uint4 index
  const float4* xf = (const float4*)x;
  float4 f0 = xf[q*2], f1 = xf[q*2+1];
  uint4 pk;
  pk.x = pack2bf(f0.x, f0.y);
  pk.y = pack2bf(f0.z, f0.w);
  pk.z = pack2bf(f1.x, f1.y);
  pk.w = pack2bf(f1.z, f1.w);
  *(uint4*)(x16 + (size_t)q*4) = pk;
}

// ================= pack W -> bf16x2 [col][kpair] =================
__global__ __launch_bounds__(256) void packw_kernel(const float* __restrict__ W, unsigned* __restrict__ W16)
{
  int q = blockIdx.x*256 + threadIdx.x;   // 0..8191
  int c = q & 127, kp = q >> 7;
  float f0 = W[(size_t)(2*kp  )*128 + c];
  float f1 = W[(size_t)(2*kp+1)*128 + c];
  W16[c*64 + kp] = pack2bf(f0, f1);
}

// ================= GEMM (bf16 MFMA) for all 4 layers =================
// layer0: adds attn rank-1 term sAttn[row]*sExtra[col] in epilogue
__global__ __launch_bounds__(256) void gemm16_kernel(
    const unsigned* __restrict__ A16, const unsigned* __restrict__ W16,
    unsigned* __restrict__ out,
    const int* __restrict__ sid, const float* __restrict__ sattn,
    const float* __restrict__ wextra, int layer0)
{
  __shared__ unsigned lds[16384];
  __shared__ float sAttn[128];
  __shared__ float sExtra[128];
  int tid = threadIdx.x;
  int lane = tid & 63;
  int row0 = blockIdx.x * 128;

  if (layer0 && tid < 128) {
    int n = row0 + tid;
    sAttn[tid]  = (n < NN) ? sattn[sid[n]] : 0.0f;
    sExtra[tid] = wextra[tid];
  }

  #pragma unroll
  for (int p = 0; p < 8; ++p) {
    int q  = tid + 256*p;
    int r  = q >> 4;
    int ch = q & 15;
    int n = row0 + r;
    uint4 v = make_uint4(0u,0u,0u,0u);
    if (n < NN) v = *(const uint4*)(A16 + (size_t)n*64 + ch*4);
    int idx = (r*64 + ch*4) ^ ((r & 7) << 2);
    *(uint4*)&lds[idx] = v;
  }
  {
    const uint4* w4 = (const uint4*)W16;
    #pragma unroll
    for (int p = 0; p < 8; ++p) {
      int ch = tid + 256*p;
      int base = ch*4;
      int c = base >> 6;
      int idx = 8192 + (base ^ ((c & 7) << 2));
      *(uint4*)&lds[idx] = w4[ch];
    }
  }
  __syncthreads();

  int w = tid >> 6;
  int wrow = w * 32;
  int swz = (lane & 7) << 2;
  int kgrp = (lane >> 4) * 4;

  f32x4 acc0[8], acc1[8];
  #pragma unroll
  for (int j = 0; j < 8; ++j) { acc0[j] = (f32x4){0,0,0,0}; acc1[j] = (f32x4){0,0,0,0}; }

  #pragma unroll
  for (int kk = 0; kk < 4; ++kk) {
    int kbase = kk*16 + kgrp;
    int rowA0 = wrow + (lane & 15);
    int rowA1 = wrow + 16 + (lane & 15);
    uint4 avu0 = *(const uint4*)&lds[(rowA0*64 + kbase) ^ swz];
    uint4 avu1 = *(const uint4*)&lds[(rowA1*64 + kbase) ^ swz];
    s16x8 a0 = as_s16x8(avu0);
    s16x8 a1 = as_s16x8(avu1);
    #pragma unroll
    for (int j = 0; j < 8; ++j) {
      int col = j*16 + (lane & 15);
      uint4 bvu = *(const uint4*)&lds[8192 + ((col*64 + kbase) ^ swz)];
      s16x8 bfr = as_s16x8(bvu);
      acc0[j] = __builtin_amdgcn_mfma_f32_16x16x32_bf16(a0, bfr, acc0[j], 0, 0, 0);
      acc1[j] = __builtin_amdgcn_mfma_f32_16x16x32_bf16(a1, bfr, acc1[j], 0, 0, 0);
    }
  }
  __syncthreads();

  #pragma unroll
  for (int i2 = 0; i2 < 2; ++i2) {
    #pragma unroll
    for (int j = 0; j < 8; ++j) {
      f32x4 v = i2 ? acc1[j] : acc0[j];
      #pragma unroll
      for (int reg = 0; reg < 4; ++reg) {
        float own = v[reg];
        int r  = wrow + i2*16 + (lane >> 4)*4 + reg;
        if (layer0) {
          int col = j*16 + (lane & 15);
          own += sAttn[r] * sExtra[col];
        }
        float part = __shfl_xor(own, 1, 64);
        if ((lane & 1) == 0) {
          int cp = j*8 + ((lane & 15) >> 1);
          lds[r*68 + cp] = pack2bf(own, part);
        }
      }
    }
  }
  __syncthreads();

  #pragma unroll
  for (int p = 0; p < 8; ++p) {
    int q  = tid + 256*p;
    int r  = q >> 4;
    int ch = q & 15;
    int n = row0 + r;
    if (n < NN) {
      uint4 v = *(const uint4*)&lds[r*68 + ch*4];
      *(uint4*)(out + (size_t)n*64 + ch*4) = v;
    }
  }
}

// ================= gather: 2 nodes per wave, 8 row-gathers in flight =======
__global__ __launch_bounds__(256) void gather_kernel(
    const unsigned* __restrict__ hw, const int* __restrict__ row_off,
    const int* __restrict__ csr_src,
    const float* __restrict__ dinv, const float* __restrict__ bias,
    const float* __restrict__ gma, const float* __restrict__ bta,
    const float* __restrict__ rmn, const float* __restrict__ rvr,
    unsigned* __restrict__ out, int relu_act)
{
  int w = (blockIdx.x*256 + threadIdx.x) >> 6;
  int lane = threadIdx.x & 63;
  int n0 = w * 2;
  if (n0 >= NN) return;
  n0 = __builtin_amdgcn_readfirstlane(n0);
  int n1 = n0 + 1;
  int j0 = lane * 2;

  float di0 = dinv[n0], di1 = dinv[n1];
  unsigned su0 = hw[(size_t)n0*64 + lane];
  unsigned su1 = hw[(size_t)n1*64 + lane];
  float ax0 = bf_lo(su0)*di0*di0, ay0 = bf_hi(su0)*di0*di0;
  float ax1 = bf_lo(su1)*di1*di1, ay1 = bf_hi(su1)*di1*di1;

  int b0 = __builtin_amdgcn_readfirstlane(row_off[n0]);
  int e0 = __builtin_amdgcn_readfirstlane(row_off[n0+1]);
  int e1 = __builtin_amdgcn_readfirstlane(row_off[n1+1]);
  int i0 = b0, i1 = e0;

  for (; i0 + 4 <= e0 && i1 + 4 <= e1; i0 += 4, i1 += 4) {
    int s00 = csr_src[i0+0], s01 = csr_src[i0+1], s02 = csr_src[i0+2], s03 = csr_src[i0+3];
    int s10 = csr_src[i1+0], s11 = csr_src[i1+1], s12 = csr_src[i1+2], s13 = csr_src[i1+3];
    unsigned u00 = hw[(size_t)s00*64 + lane];
    unsigned u01 = hw[(size_t)s01*64 + lane];
    unsigned u02 = hw[(size_t)s02*64 + lane];
    unsigned u03 = hw[(size_t)s03*64 + lane];
    unsigned u10 = hw[(size_t)s10*64 + lane];
    unsigned u11 = hw[(size_t)s11*64 + lane];
    unsigned u12 = hw[(size_t)s12*64 + lane];
    unsigned u13 = hw[(size_t)s13*64 + lane];
    float c00 = dinv[s00]*di0, c01 = dinv[s01]*di0, c02 = dinv[s02]*di0, c03 = dinv[s03]*di0;
    float c10 = dinv[s10]*di1, c11 = dinv[s11]*di1, c12 = dinv[s12]*di1, c13 = dinv[s13]*di1;
    ax0 += bf_lo(u00)*c00 + bf_lo(u01)*c01 + bf_lo(u02)*c02 + bf_lo(u03)*c03;
    ay0 += bf_hi(u00)*c00 + bf_hi(u01)*c01 + bf_hi(u02)*c02 + bf_hi(u03)*c03;
    ax1 += bf_lo(u10)*c10 + bf_lo(u11)*c11 + bf_lo(u12)*c12 + bf_lo(u13)*c13;
    ay1 += bf_hi(u10)*c10 + bf_hi(u11)*c11 + bf_hi(u12)*c12 + bf_hi(u13)*c13;
  }
  for (; i0 + 4 <= e0; i0 += 4) {
    int s0 = csr_src[i0+0], s1 = csr_src[i0+1], s2 = csr_src[i0+2], s3 = csr_src[i0+3];
    unsigned u0 = hw[(size_t)s0*64 + lane];
    unsigned u1 = hw[(size_t)s1*64 + lane];
    unsigned u2 = hw[(size_t)s2*64 + lane];
    unsigned u3 = hw[(size_t)s3*64 + lane];
    float c0 = dinv[s0]*di0, c1 = dinv[s1]*di0, c2 = dinv[s2]*di0, c3 = dinv[s3]*di0;
    ax0 += bf_lo(u0)*c0 + bf_lo(u1)*c1 + bf_lo(u2)*c2 + bf_lo(u3)*c3;
    ay0 += bf_hi(u0)*c0 + bf_hi(u1)*c1 + bf_hi(u2)*c2 + bf_hi(u3)*c3;
  }
  for (; i1 + 4 <= e1; i1 += 4) {
    int s0 = csr_src[i1+0], s1 = csr_src[i1+1], s2 = csr_src[i1+2], s3 = csr_src[i1+3];
    unsigned u0 = hw[(size_t)s0*64 + lane];
    unsigned u1 = hw[(size_t)s1*64 + lane];
    unsigned u2 = hw[(size_t)s2*64 + lane];
    unsigned u3 = hw[(size_t)s3*64 + lane];
    float c0 = dinv[s0]*di1, c1 = dinv[s1]*di1, c2 = dinv[s2]*di1, c3 = dinv[s3]*di1;
    ax1 += bf_lo(u0)*c0 + bf_lo(u1)*c1 + bf_lo(u2)*c2 + bf_lo(u3)*c3;
    ay1 += bf_hi(u0)*c0 + bf_hi(u1)*c1 + bf_hi(u2)*c2 + bf_hi(u3)*c3;
  }
  for (; i0 < e0; ++i0) {
    int s = csr_src[i0];
    float c = dinv[s]*di0;
    unsigned u = hw[(size_t)s*64 + lane];
    ax0 += bf_lo(u)*c; ay0 += bf_hi(u)*c;
  }
  for (; i1 < e1; ++i1) {
    int s = csr_src[i1];
    float c = dinv[s]*di1;
    unsigned u = hw[(size_t)s*64 + lane];
    ax1 += bf_lo(u)*c; ay1 += bf_hi(u)*c;
  }

  float iv0 = rsqrtf(rvr[j0]   + 1e-5f);
  float iv1 = rsqrtf(rvr[j0+1] + 1e-5f);
  float g0 = gma[j0], g1 = gma[j0+1];
  float m0 = rmn[j0], m1 = rmn[j0+1];
  float t0 = bta[j0], t1 = bta[j0+1];
  float bb0 = bias[j0], bb1 = bias[j0+1];

  float y00 = (ax0 + bb0 - m0) * iv0 * g0 + t0;
  float y01 = (ay0 + bb1 - m1) * iv1 * g1 + t1;
  float y10 = (ax1 + bb0 - m0) * iv0 * g0 + t0;
  float y11 = (ay1 + bb1 - m1) * iv1 * g1 + t1;
  if (relu_act) {
    y00 = fmaxf(y00, 0.0f); y01 = fmaxf(y01, 0.0f);
    y10 = fmaxf(y10, 0.0f); y11 = fmaxf(y11, 0.0f);
  } else {
    y00 = (y00 > 0.0f) ? y00 : expm1f(y00);
    y01 = (y01 > 0.0f) ? y01 : expm1f(y01);
    y10 = (y10 > 0.0f) ? y10 : expm1f(y10);
    y11 = (y11 > 0.0f) ? y11 : expm1f(y11);
  }
  out[(size_t)n0*64 + lane] = pack2bf(y00, y01);
  out[(size_t)n1*64 + lane] = pack2bf(y10, y11);
}

// ================= graph starts / pool / head =================
__global__ __launch_bounds__(256) void gstart_kernel(const int* __restrict__ batch, int* __restrict__ start)
{
  int n = blockIdx.x*256 + threadIdx.x;
  if (n >= NN) return;
  int b  = batch[n];
  int bp = (n == 0) ? -1 : batch[n-1];
  for (int g = bp + 1; g <= b; ++g) start[g] = n;
  if (n == NN-1) {
    for (int g = b + 1; g <= GG; ++g) start[g] = NN;
  }
}

__global__ __launch_bounds__(256) void pool_kernel(
    const unsigned* __restrict__ h16, const int* __restrict__ batch, float* __restrict__ pooled)
{
  int wave = (blockIdx.x*256 + threadIdx.x) >> 6;
  int lane = threadIdx.x & 63;
  const int CH = 64;
  int beg = wave * CH;
  if (beg >= NN) return;
  int end = min(beg + CH, NN);
  int j0 = lane * 2;
  float ax = 0.f, ay = 0.f;
  int gcur = batch[beg];
  for (int n = beg; n < end; ++n) {
    int g = batch[n];
    if (g != gcur) {
      atomicAdd(&pooled[(size_t)gcur*128 + j0],     ax);
      atomicAdd(&pooled[(size_t)gcur*128 + j0 + 1], ay);
      ax = 0.f; ay = 0.f; gcur = g;
    }
    unsigned u = h16[(size_t)n*64 + lane];
    ax += bf_lo(u); ay += bf_hi(u);
  }
  atomicAdd(&pooled[(size_t)gcur*128 + j0],     ax);
  atomicAdd(&pooled[(size_t)gcur*128 + j0 + 1], ay);
}

__global__ __launch_bounds__(64) void head_kernel(
    const float* __restrict__ pooled, const int* __restrict__ start,
    const float* __restrict__ w1, const float* __restrict__ b1,
    const float* __restrict__ w2, const float* __restrict__ b2,
    float* __restrict__ out)
{
  __shared__ float p[128];
  int g = blockIdx.x;
  int t = threadIdx.x;
  float cnt = fmaxf((float)(start[g+1] - start[g]), 1.0f);
  p[t]      = pooled[(size_t)g*128 + t]      / cnt;
  p[t + 64] = pooled[(size_t)g*128 + t + 64] / cnt;
  __syncthreads();
  float a = 0.f;
  #pragma unroll 4
  for (int d = 0; d < 128; ++d) a += p[d] * w1[d*64 + t];
  float z = a + b1[t];
  z = (z > 0.f) ? z : expm1f(z);
  float v = z * w2[t];
  #pragma unroll
  for (int off = 32; off > 0; off >>= 1) v += __shfl_down(v, off, 64);
  if (t == 0) out[g] = v + b2[0];
}

extern "C" void kernel_launch(void* const* d_in, const int* in_sizes, int n_in,
                              void* d_out, int out_size, void* d_ws, size_t ws_size,
                              hipStream_t stream)
{
  const float* x        = (const float*)d_in[0];
  const int*   eidx     = (const int*)d_in[1];
  const int*   sid      = (const int*)d_in[2];
  const int*   batch    = (const int*)d_in[3];
  const float* attn_w1  = (const float*)d_in[4];
  const float* attn_b1  = (const float*)d_in[5];
  const float* attn_w2  = (const float*)d_in[6];
  const float* conv_w[4] = {(const float*)d_in[7], (const float*)d_in[9],
                            (const float*)d_in[11], (const float*)d_in[13]};
  const float* conv_b[4] = {(const float*)d_in[8], (const float*)d_in[10],
                            (const float*)d_in[12], (const float*)d_in[14]};
  const float* bn_gamma = (const float*)d_in[15];
  const float* bn_beta  = (const float*)d_in[16];
  const float* bn_rmean = (const float*)d_in[17];
  const float* bn_rvar  = (const float*)d_in[18];
  const float* head_w1  = (const float*)d_in[19];
  const float* head_b1  = (const float*)d_in[20];
  const float* head_w2  = (const float*)d_in[21];
  const float* head_b2  = (const float*)d_in[22];
  float* out = (float*)d_out;

  char* ws = (char*)d_ws;
  unsigned* buf0  = (unsigned*)(ws + OFF_HW);
  unsigned* buf1  = (unsigned*)(ws + OFF_H);
  unsigned* x16   = (unsigned*)(ws + OFF_X16);
  int*   csr_src  = (int*)  (ws + OFF_CSRS);
  int*   row_off  = (int*)  (ws + OFF_ROW);
  float* dinv     = (float*)(ws + OFF_DINV);
  float* sattn    = (float*)(ws + OFF_SATT);
  int*   gstart   = (int*)  (ws + OFF_GST);
  int*   bhist    = (int*)  (ws + OFF_BH);
  int*   boff2    = (int*)  (ws + OFF_BO);
  int*   tots     = (int*)  (ws + OFF_TOT);
  int*   row2     = (int*)  (ws + OFF_ROW2);
  unsigned* list  = (unsigned*)(ws + OFF_LIST);
  unsigned* w16   = (unsigned*)(ws + OFF_W16);
  int*   ehist    = (int*)  (ws + OFF_EH);
  int*   eboff    = (int*)  (ws + OFF_EB);
  int*   etots    = (int*)  (ws + OFF_ET);
  int*   ebase    = (int*)  (ws + OFF_EBASE);
  unsigned* epk   = (unsigned*)(ws + OFF_EPK);
  float* pooled   = (float*)(ws + OFF_POOL);
  float* gsum     = (float*)(ws + OFF_GSUM);

  const int* e_src = eidx;
  const int* e_dst = eidx + EE;

  hipMemsetAsync(ws + ZERO_BEG, 0, ZERO_BYTES, stream);

  int nb256 = (NN + 255)/256;  // 391

  // pack x first (feeds subst_sum and layer-0 GEMM)
  packx_kernel<<<(NN*16)/256, 256, 0, stream>>>(x, x16);
  for (int L = 0; L < 4; ++L)
    packw_kernel<<<32, 256, 0, stream>>>(conv_w[L], w16 + (size_t)L*8192);

  // substructure attention (subst_sum reads bf16 x16 -> half the traffic)
  hist_kernel <<<nb256, 256, 0, stream>>>(sid, bhist);
  offs_kernel <<<64, 512, 0, stream>>>(bhist, boff2, tots);
  base_kernel <<<1, 64, 0, stream>>>(tots, row2);
  fill2_kernel<<<nb256, 256, 0, stream>>>(sid, row2, boff2, list);
  subst_sum   <<<1024, 256, 0, stream>>>(list, x16, gsum);
  attn_kernel <<<1, 1024, 0, stream>>>(gsum, row2, attn_w1, attn_b1, attn_w2, sattn);

  // CSR via dst bucketing (no global atomics, packed edges)
  ehist_kernel<<<NBE, 256, 0, stream>>>(e_dst, ehist);
  eoffs_kernel<<<EBK, 1024, 0, stream>>>(ehist, eboff, etots);
  ebase_kernel<<<1, 256, 0, stream>>>(etots, ebase);
  escat_kernel<<<NBE, 256, 0, stream>>>(e_src, e_dst, ebase, eboff, epk);
  csr_build   <<<EBK, 1024, 0, stream>>>(ebase, epk, row_off, dinv, csr_src);

  gstart_kernel<<<nb256, 256, 0, stream>>>(batch, gstart);

  int gemm_grid = (NN + 127)/128;        // 782
  int gat_grid  = ((NN/2)*64 + 255)/256; // 12500
  for (int L = 0; L < 4; ++L) {
    const unsigned* A = (L == 0) ? x16 : buf1;
    gemm16_kernel<<<gemm_grid, 256, 0, stream>>>(A, w16 + (size_t)L*8192, buf0,
        sid, sattn, conv_w[0] + 128*128, (L == 0) ? 1 : 0);
    gather_kernel<<<gat_grid, 256, 0, stream>>>(buf0, row_off, csr_src, dinv,
        conv_b[L], bn_gamma + L*HH, bn_beta + L*HH, bn_rmean + L*HH, bn_rvar + L*HH,
        buf1, (L == 3) ? 1 : 0);
  }

  int pool_waves  = (NN + 63)/64;               // 1563
  int pool_blocks = (pool_waves + 3)/4;         // 391
  pool_kernel<<<pool_blocks, 256, 0, stream>>>(buf1, batch, pooled);
  head_kernel<<<GG, 64, 0, stream>>>(pooled, gstart, head_w1, head_b1, head_w2, head_b2, out);
}